// Round 1
// baseline (208.604 us; speedup 1.0000x reference)
//
#include <hip/hip_runtime.h>
#include <stdint.h>
#include <stddef.h>

// Problem constants
#define B_ 4
#define L_ 8192
#define D_ 512
#define M_ (B_*L_)      // 32768 rows
#define K_ 512
#define CHUNK 64
#define NC (L_/CHUNK)   // 128 chunks per sequence

typedef _Float16 f16;
typedef f16 f16x2 __attribute__((ext_vector_type(2)));
typedef f16 f16x4 __attribute__((ext_vector_type(4)));
typedef f16 f16x8 __attribute__((ext_vector_type(8)));
typedef float f32x4 __attribute__((ext_vector_type(4)));

// ---------------- async global->LDS (16B/lane) ----------------
__device__ __forceinline__ void async16(const void* g, void* l) {
  __builtin_amdgcn_global_load_lds(
      (const __attribute__((address_space(1))) uint32_t*)g,
      (__attribute__((address_space(3))) uint32_t*)l,
      16, 0, 0);
}

// ---------------- prep: fused cvt_x + pack_w (one dispatch) ----------------
// blocks [0, 16384): convert x fp32 -> f16
// blocks [16384, 16896): pack Wg ++ Wc into f16 [1024][512]
__global__ __launch_bounds__(256) void prep(const float* __restrict__ x,
                                            const float* __restrict__ Wg,
                                            const float* __restrict__ Wc,
                                            f16* __restrict__ xh,
                                            f16* __restrict__ wp) {
  const int bid = blockIdx.x;
  if (bid < 16384) {
    const int idx = (bid * 256 + threadIdx.x) * 4;
    float4 v = *(const float4*)(x + idx);
    f16x4 o = {(f16)v.x, (f16)v.y, (f16)v.z, (f16)v.w};
    *(f16x4*)(xh + idx) = o;
  } else {
    const int idx = ((bid - 16384) * 256 + threadIdx.x) * 4;  // 0..524287
    const float* src = (idx < 262144) ? (Wg + idx) : (Wc + (idx - 262144));
    float4 v = *(const float4*)src;
    f16x4 o = {(f16)v.x, (f16)v.y, (f16)v.z, (f16)v.w};
    *(f16x4*)(wp + idx) = o;
  }
}

// ---------------- fused dual-B GEMM + activations + chunk composites ------
// Per block: A-tile 128 rows (= 2 chunks of 64), ONE 128-col tile, BOTH weights.
// yg = Xh·Wg^T + bg ; yc = Xh·Wc^T + bc
// a = 1 - sigmoid(yg); b = sigmoid(yg) * tanh(yc)
// AC[m*512 + col] = pack_f16x2(a, b)
// Epilogue ALSO computes per-chunk affine composite (P,Q) over t=0..63 per col
// (in-lane over r, cross-quad shfl tree, then 4 i-blocks) -> cA/cB.
// This replaces the former scan_local pass (kills a 64MB HBM re-read).
__global__ __launch_bounds__(256, 2) void gemm_act(
    const f16* __restrict__ Xh, const f16* __restrict__ Wp,
    const float* __restrict__ bg, const float* __restrict__ bc,
    uint32_t* __restrict__ AC,
    float* __restrict__ cA, float* __restrict__ cB) {
  __shared__ __align__(16) f16 sA[128 * 32];
  __shared__ __align__(16) f16 sBg[128 * 32];
  __shared__ __align__(16) f16 sBc[128 * 32];

  const int tid = threadIdx.x;
  // XCD swizzle: same bm-tile's 4 col-blocks run consecutively on one XCD
  const int id = blockIdx.x;           // 0..1023
  const int xcd = id & 7;
  const int slot = id >> 3;            // 0..127
  const int g_ = xcd * 128 + slot;
  const int bm = g_ >> 2;              // 0..255
  const int bn = g_ & 3;               // 0..3 (128-col tiles)

  const int lane = tid & 63;
  const int w = tid >> 6;
  const int wm = w >> 1, wn = w & 1;   // 2x2 wave grid over 128x128
  const int l15 = lane & 15, quad = lane >> 4;

  // staging: tid -> (row = tid>>2, 16B piece = tid&3); covers 64 rows/round
  const int srow = tid >> 2;
  const int spc8 = (tid & 3) * 8;
  const f16* gA  = Xh + (size_t)(bm * 128 + srow) * K_ + spc8;
  const f16* gBg = Wp + (size_t)(bn * 128 + srow) * K_ + spc8;
  const f16* gBc = Wp + (size_t)(512 + bn * 128 + srow) * K_ + spc8;
  f16* lA  = sA  + tid * 8;
  f16* lBg = sBg + tid * 8;
  f16* lBc = sBc + tid * 8;

  f32x4 accG[4][4] = {};
  f32x4 accC[4][4] = {};

  for (int k0 = 0; k0 < K_; k0 += 32) {
    async16(gA + k0,  lA);
    async16(gA + (size_t)64 * K_ + k0,  lA  + 64 * 32);
    async16(gBg + k0, lBg);
    async16(gBg + (size_t)64 * K_ + k0, lBg + 64 * 32);
    async16(gBc + k0, lBc);
    async16(gBc + (size_t)64 * K_ + k0, lBc + 64 * 32);
    __syncthreads();  // drains vmcnt then barrier

    f16x8 af[4], bgf[4], bcf[4];
#pragma unroll
    for (int i = 0; i < 4; i++)
      af[i]  = *(const f16x8*)(sA  + (wm * 64 + i * 16 + l15) * 32 + quad * 8);
#pragma unroll
    for (int j = 0; j < 4; j++) {
      bgf[j] = *(const f16x8*)(sBg + (wn * 64 + j * 16 + l15) * 32 + quad * 8);
      bcf[j] = *(const f16x8*)(sBc + (wn * 64 + j * 16 + l15) * 32 + quad * 8);
    }
#pragma unroll
    for (int i = 0; i < 4; i++)
#pragma unroll
      for (int j = 0; j < 4; j++) {
        accG[i][j] = __builtin_amdgcn_mfma_f32_16x16x32_f16(af[i], bgf[j], accG[i][j], 0, 0, 0);
        accC[i][j] = __builtin_amdgcn_mfma_f32_16x16x32_f16(af[i], bcf[j], accC[i][j], 0, 0, 0);
      }
    __syncthreads();
  }

  // Epilogue: sigmoid/tanh, pack (a,b) f16x2 -> AC, and per-chunk (P,Q).
  // Wave (wm) owns rows [wm*64, wm*64+64) = exactly chunk c.
  // Within chunk, time index t = i*16 + quad*4 + r (lexicographic i,quad,r).
  const int c = bm * 2 + wm;           // global chunk index 0..511
#pragma unroll
  for (int j = 0; j < 4; j++) {
    const int col = bn * 128 + wn * 64 + j * 16 + l15;   // 0..511
    const float bgv = bg[col];
    const float bcv = bc[col];
    float blkP[4], blkQ[4];
#pragma unroll
    for (int i = 0; i < 4; i++) {
      const int mrow = bm * 128 + wm * 64 + i * 16 + quad * 4;
      float P = 1.0f, Q = 0.0f;
#pragma unroll
      for (int r = 0; r < 4; r++) {
        float yg = accG[i][j][r] + bgv;
        float gg = 1.0f / (1.0f + __expf(-yg));        // sigmoid
        float yc = accC[i][j][r] + bcv;
        yc = fminf(fmaxf(yc, -15.0f), 15.0f);
        float t = __expf(2.0f * yc);
        float cc = (t - 1.0f) / (t + 1.0f);            // tanh
        f16x2 p;
        p[0] = (f16)(1.0f - gg);                        // a
        p[1] = (f16)(gg * cc);                          // b
        *(f16x2*)&AC[(size_t)(mrow + r) * 512 + col] = p;
        // compose with the SAME f16-rounded values scan_apply will read
        const float av = (float)p[0];
        const float bv = (float)p[1];
        Q = fmaf(av, Q, bv);                            // seg over r (t asc)
        P *= av;
      }
      // ordered cross-quad compose: quads 0..3 are consecutive t-segments.
      // comp(first,second) = (Ps*Pf, Ps*Qf + Qs)
      float Pp = __shfl_xor(P, 16);
      float Qp = __shfl_xor(Q, 16);
      float nP = P * Pp;
      float nQ = (quad & 1) ? fmaf(P, Qp, Q) : fmaf(Pp, Q, Qp);
      Pp = __shfl_xor(nP, 32);
      Qp = __shfl_xor(nQ, 32);
      blkP[i] = nP * Pp;
      blkQ[i] = (quad & 2) ? fmaf(nP, Qp, nQ) : fmaf(Pp, nQ, Qp);
    }
    // compose the 4 sixteen-row blocks in t order
    float CP = blkP[0], CQ = blkQ[0];
#pragma unroll
    for (int i = 1; i < 4; i++) {
      CQ = fmaf(blkP[i], CQ, blkQ[i]);
      CP *= blkP[i];
    }
    if (quad == 0) {
      cA[(size_t)c * 512 + col] = CP;
      cB[(size_t)c * 512 + col] = CQ;
    }
  }
}

// ---------------- scan: inline chunk-prefix + apply, 8B/lane ----------------
// Each block = one chunk (b, ch). Thread owns 2 consecutive d columns.
// Prefix over chunks 0..ch-1 from cA/cB (2MB total, L2-resident), then the
// 64-step within-chunk recurrence, writing fp32 h. Replaces scan_chunks +
// scan_apply (no Hpre round-trip, no cross-kernel serialization point).
__global__ __launch_bounds__(256) void scan_apply(
    const uint32_t* __restrict__ AC,
    const float* __restrict__ cA, const float* __restrict__ cB,
    float* __restrict__ out) {
  const int blk = blockIdx.x;          // 0..511 = b*NC + ch
  const int ch = blk & (NC - 1);
  const int bseq = blk >> 7;           // NC = 128
  const int d0 = threadIdx.x * 2;

  float h0 = 0.0f, h1 = 0.0f;
  const float* pA = cA + (size_t)(bseq * NC) * 512 + d0;
  const float* pB = cB + (size_t)(bseq * NC) * 512 + d0;
#pragma unroll 4
  for (int cc = 0; cc < ch; cc++) {
    float2 va = *(const float2*)(pA + (size_t)cc * 512);
    float2 vb = *(const float2*)(pB + (size_t)cc * 512);
    h0 = fmaf(va.x, h0, vb.x);
    h1 = fmaf(va.y, h1, vb.y);
  }

  const size_t base = (size_t)blk * CHUNK * 512 + d0;
#pragma unroll 8
  for (int t = 0; t < CHUNK; t++) {
    const size_t i = base + (size_t)t * 512;
    uint2 v = *(const uint2*)&AC[i];
    f16x2 p0 = __builtin_bit_cast(f16x2, v.x);
    f16x2 p1 = __builtin_bit_cast(f16x2, v.y);
    h0 = fmaf((float)p0[0], h0, (float)p0[1]);
    h1 = fmaf((float)p1[0], h1, (float)p1[1]);
    float2 o;
    o.x = h0;
    o.y = h1;
    *(float2*)&out[i] = o;
  }
}

// ---------------- launch ----------------
extern "C" void kernel_launch(void* const* d_in, const int* in_sizes, int n_in,
                              void* d_out, int out_size, void* d_ws, size_t ws_size,
                              hipStream_t stream) {
  const float* x  = (const float*)d_in[0];
  const float* Wg = (const float*)d_in[1];
  const float* bg = (const float*)d_in[2];
  const float* Wc = (const float*)d_in[3];
  const float* bc = (const float*)d_in[4];
  float* out = (float*)d_out;

  char* ws = (char*)d_ws;
  // workspace layout (bytes):
  //   [0, 32MB)      xh   f16 x
  //   [32MB, 33MB)   wp   f16 packed weights [1024][512]
  //   [33MB, 97MB)   AC   u32 packed (a,b) f16x2 [32768][512]
  //   [97MB..]       cA, cB fp32 (1MB each)
  f16*      xh = (f16*)(ws);
  f16*      wp = (f16*)(ws + 33554432);
  uint32_t* AC = (uint32_t*)(ws + 34603008);
  float*    cA = (float*)(ws + 101711872);
  float*    cB = (float*)(ws + 102760448);

  prep<<<16896, 256, 0, stream>>>(x, Wg, Wc, xh, wp);                 // cvt + pack
  gemm_act<<<(M_ / 128) * 4, 256, 0, stream>>>(xh, wp, bg, bc, AC, cA, cB); // 1024 blocks
  scan_apply<<<B_ * NC, 256, 0, stream>>>(AC, cA, cB, out);           // 512 blocks
}